// Round 8
// baseline (143.617 us; speedup 1.0000x reference)
//
#include <hip/hip_runtime.h>

// Problem constants (compile-time, from reference):
//   B=2, D=H=W=160, C=2, N_LABELS=25, MAX_LABEL=48
//   voxels/batch V = 160^3 = 4,096,000 ; total voxels = 8,192,000
#define VPB   4096000
#define NLAB  25
#define TOTAL_VOX 8192000

// GEN_LABELS = {0,2,3,4,5,7,8,10,11,12,13,14,15,16,17,18,24,26,28,41,42,43,44,46,47}
// encoded as a 48-bit mask; row(label) = popcount(mask & ((1<<label)-1)).
#define GEN_MASK 0x0000DE001507FDBDull

// Round-11 (2nd resubmit after broker timeouts): depth, not structure. r10
// proved block-coupling was NOT the limiter (register-shuffle kernel ==
// LDS-table kernel == ~41.5 us, no pipe saturated, effective BW 4.0 TB/s vs
// 6.3 copy ceiling). Remaining theories:
//   (1) latency/queueing: only 2 loads in flight per wave + 64K short waves
//       (occupancy stuck at 67% with unbounded grid = slot-refill limited)
//   (2) genuine ~4 TB/s mixed-stream floor.
// This kernel tests (1): 8 vox/thread as 4 independent 2-vox chunks, ALL 8
// streaming loads issued before any compute (96 B/thread in flight), waves
// 64K -> 16K. Chunk->batch mapping is compile-time (chunks 0-1 batch 0,
// 2-3 batch 1). All register arrays statically indexed (#pragma unroll).
// Round-3 lesson kept: NO nontemporal stores (1.74x WRITE_SIZE amplification).
#define NBLK   4000
#define GSTRIDE (NBLK * 256)            // 1,024,000 threads
#define CHUNKV  (GSTRIDE * 2)           // 2,048,000 voxels per chunk

__global__ __launch_bounds__(256) void gmm_sample_kernel(
    const int*   __restrict__ labels,   // [B*V] (trailing dim 1 squeezed)
    const float* __restrict__ means,    // [B, 25, 2]
    const float* __restrict__ stds,     // [B, 25, 2]
    const float* __restrict__ noise,    // [B*V, 2]
    float*       __restrict__ out)      // [B*V, 2]
{
    const int tid  = threadIdx.x;
    const int g    = blockIdx.x * 256 + tid;    // < 1,024,000
    const int lane = tid & 63;

    // per-lane register table: lane l holds entries for label VALUE l (0..47)
    int row = (int)__popcll(GEN_MASK & ((1ull << lane) - 1ull));
    row = row < NLAB ? row : NLAB - 1;          // lanes 48-63: clamp (unused)

    // Both batches' table entries, loaded once per thread (L1-hot 800 B total).
    const float2 m0 = *(const float2*)(means + (row << 1));
    const float2 s0 = *(const float2*)(stds  + (row << 1));
    const float2 m1 = *(const float2*)(means + ((NLAB + row) << 1));
    const float2 s1 = *(const float2*)(stds  + ((NLAB + row) << 1));

    // ---- issue ALL streaming loads first: 8 loads in flight per thread ----
    int2   lab[4];
    float4 nz[4];
#pragma unroll
    for (int i = 0; i < 4; ++i) {
        const size_t v0 = (size_t)i * CHUNKV + ((size_t)g << 1);
        lab[i] = *(const int2*)  (labels + v0);
        nz[i]  = *(const float4*)(noise + (v0 << 1));
    }

    // ---- per-chunk gather (ds_bpermute) + fma + store ----
#pragma unroll
    for (int i = 0; i < 4; ++i) {
        const size_t v0 = (size_t)i * CHUNKV + ((size_t)g << 1);
        // chunk 0-1: batch 0 ; chunk 2-3: batch 1 (compile-time select)
        const float2 m = (i >= 2) ? m1 : m0;
        const float2 s = (i >= 2) ? s1 : s0;

        const float e0x = __shfl(m.x, lab[i].x, 64);
        const float e0y = __shfl(m.y, lab[i].x, 64);
        const float e0z = __shfl(s.x, lab[i].x, 64);
        const float e0w = __shfl(s.y, lab[i].x, 64);
        const float e1x = __shfl(m.x, lab[i].y, 64);
        const float e1y = __shfl(m.y, lab[i].y, 64);
        const float e1z = __shfl(s.x, lab[i].y, 64);
        const float e1w = __shfl(s.y, lab[i].y, 64);

        float4 o;
        o.x = fmaf(e0z, nz[i].x, e0x);
        o.y = fmaf(e0w, nz[i].y, e0y);
        o.z = fmaf(e1z, nz[i].z, e1x);
        o.w = fmaf(e1w, nz[i].w, e1y);

        *(float4*)(out + (v0 << 1)) = o;
    }
}

extern "C" void kernel_launch(void* const* d_in, const int* in_sizes, int n_in,
                              void* d_out, int out_size, void* d_ws, size_t ws_size,
                              hipStream_t stream) {
    const int*   labels = (const int*)  d_in[0];  // [2,160,160,160,1] int32
    const float* means  = (const float*)d_in[1];  // [2,25,2] f32
    const float* stds   = (const float*)d_in[2];  // [2,25,2] f32
    const float* noise  = (const float*)d_in[3];  // [2,160,160,160,2] f32
    float* out = (float*)d_out;                   // [2,160,160,160,2] f32

    // 4000 blocks x 256 threads x 2 vox x 4 chunks = 8,192,000 voxels exactly
    gmm_sample_kernel<<<NBLK, 256, 0, stream>>>(labels, means, stds, noise, out);
}

// Round 10
// 138.170 us; speedup vs baseline: 1.0394x; 1.0394x over previous
//
#include <hip/hip_runtime.h>

// Problem constants (compile-time, from reference):
//   B=2, D=H=W=160, C=2, N_LABELS=25, MAX_LABEL=48
//   voxels/batch V = 160^3 = 4,096,000 ; total voxels = 8,192,000
#define VPB   4096000
#define NLAB  25
#define TOTAL_VOX 8192000

// GEN_LABELS = {0,2,3,4,5,7,8,10,11,12,13,14,15,16,17,18,24,26,28,41,42,43,44,46,47}
// encoded as a 48-bit mask; row(label) = popcount(mask & ((1<<label)-1)).
#define GEN_MASK 0x0000DE001507FDBDull

// Round-12 (resubmit after broker timeout): block-granularity decoupling.
// r11 killed the per-wave-ILP theory (8 loads in flight/wave REGRESSED
// 41.5->47.4 us; FETCH/WRITE identical): perf tracks wave/block count, not
// depth — tight many-wave streaming maximizes the memory system's service
// rate. Remaining untested axis: the 67% occupancy plateau. 256-thread
// blocks free their 4 wave-slots only when the LAST wave retires -> refill
// bubbles. This kernel: identical 2-vox shuffle body, 128-thread blocks
// (2 waves), 32000 blocks. (Not 64-thread: the ~16 WG/CU cap would clamp
// 1-wave blocks to 16 waves = 50%.)
// Round-3 lesson kept: NO nontemporal stores (1.74x WRITE_SIZE amplification).
__global__ __launch_bounds__(128) void gmm_sample_kernel(
    const int*   __restrict__ labels,   // [B*V] (trailing dim 1 squeezed)
    const float* __restrict__ means,    // [B, 25, 2]
    const float* __restrict__ stds,     // [B, 25, 2]
    const float* __restrict__ noise,    // [B*V, 2]
    float*       __restrict__ out)      // [B*V, 2]
{
    const int tid = threadIdx.x;
    const int g   = blockIdx.x * 128 + tid;     // thread id, < 4,096,000
    const int v0  = g << 1;                     // first voxel, < 8,192,000

    // ---- streaming loads issue first, in flight during table load ----
    const int2   lab = *(const int2*)  (labels + v0);
    const float4 n0  = *(const float4*)(noise + ((size_t)v0 << 1));

    // ---- per-lane register table: lane l holds (m0,m1,s0,s1) for label
    //      VALUE l (l in 0..47; input labels are always in GEN_LABELS) ----
    const int lane = tid & 63;
    int row = (int)__popcll(GEN_MASK & ((1ull << lane) - 1ull));
    row = row < NLAB ? row : NLAB - 1;          // lanes 48-63: clamp (data unused)

    // Batch boundary (4,096,000) = block 16000 * 256 exactly -> whole block
    // (and both voxels of each thread) lie in one batch.
    const int boff = (v0 >= VPB) ? NLAB : 0;
    const float2 m = *(const float2*)(means + ((boff + row) << 1));  // L1/L2-hot 400 B
    const float2 s = *(const float2*)(stds  + ((boff + row) << 1));

    // ---- gather = intra-wave shuffle (ds_bpermute), conflict-free ----
    const float e0x = __shfl(m.x, lab.x, 64);
    const float e0y = __shfl(m.y, lab.x, 64);
    const float e0z = __shfl(s.x, lab.x, 64);
    const float e0w = __shfl(s.y, lab.x, 64);
    const float e1x = __shfl(m.x, lab.y, 64);
    const float e1y = __shfl(m.y, lab.y, 64);
    const float e1z = __shfl(s.x, lab.y, 64);
    const float e1w = __shfl(s.y, lab.y, 64);

    float4 o0;
    o0.x = fmaf(e0z, n0.x, e0x);
    o0.y = fmaf(e0w, n0.y, e0y);
    o0.z = fmaf(e1z, n0.z, e1x);
    o0.w = fmaf(e1w, n0.w, e1y);

    *(float4*)(out + ((size_t)v0 << 1)) = o0;
}

extern "C" void kernel_launch(void* const* d_in, const int* in_sizes, int n_in,
                              void* d_out, int out_size, void* d_ws, size_t ws_size,
                              hipStream_t stream) {
    const int*   labels = (const int*)  d_in[0];  // [2,160,160,160,1] int32
    const float* means  = (const float*)d_in[1];  // [2,25,2] f32
    const float* stds   = (const float*)d_in[2];  // [2,25,2] f32
    const float* noise  = (const float*)d_in[3];  // [2,160,160,160,2] f32
    float* out = (float*)d_out;                   // [2,160,160,160,2] f32

    const int threads = 128;
    const int total_threads = TOTAL_VOX / 2;      // 4,096,000
    const int blocks = total_threads / threads;   // 32000
    gmm_sample_kernel<<<blocks, threads, 0, stream>>>(labels, means, stds, noise, out);
}